// Round 8
// baseline (446.648 us; speedup 1.0000x reference)
//
#include <hip/hip_runtime.h>
#include <cstdint>
#include <cstddef>

#define B_  64
#define D_  1024
#define S_  512
#define K_  100
#define KP_ 128
#define H_  2048
#define BS_ (B_*S_)   // 32768

// ---- workspace layout (float offsets) ----
static constexpr size_t OFF_TVN  = 0;                          // [1024][128] padded normalized topics
static constexpr size_t OFF_TPNT = 131072;                     // [100][32768] topic_prob_n transposed
static constexpr size_t OFF_HSUM = OFF_TPNT + (size_t)K_*BS_;  // [64][2048]
static constexpr size_t OFF_INTS = OFF_HSUM + (size_t)B_*H_;   // int region: cnt, bact[64], alist[32768]

// ---------------------------------------------------------------------------
// prep: blocks 0..127 normalize topic columns -> tvn[1024][128] (pad cols 0);
//       blocks 128..639 zero hsum; block 640: out scalar init + ints zero.
__global__ __launch_bounds__(256) void prep_kernel(
    const float* __restrict__ tv, const float* __restrict__ bc,
    float* __restrict__ tvn, float* __restrict__ hsum,
    int* __restrict__ ints, float* __restrict__ out)
{
    __shared__ float red[256];
    const int tid = threadIdx.x;
    const int blk = blockIdx.x;
    if (blk < KP_) {
        const int k = blk;
        if (k >= K_) {
            for (int d = tid; d < D_; d += 256) tvn[d*KP_ + k] = 0.f;
            return;
        }
        float ss = 0.f;
        for (int d = tid; d < D_; d += 256) { float v = tv[d*K_ + k]; ss = fmaf(v, v, ss); }
        red[tid] = ss;
        __syncthreads();
        for (int s = 128; s > 0; s >>= 1) {
            if (tid < s) red[tid] += red[tid + s];
            __syncthreads();
        }
        const float inv = 1.0f / fmaxf(sqrtf(red[0]), 1e-12f);
        for (int d = tid; d < D_; d += 256) tvn[d*KP_ + k] = tv[d*K_ + k] * inv;
        return;
    }
    if (blk < KP_ + 512) {
        hsum[(blk - KP_)*256 + tid] = 0.f;       // 512*256 == B_*H_
        return;
    }
    // scalar init block
    if (tid < 128)      out[tid] = bc[tid & 1];  // pred = b_cls (atomics add partials)
    else if (tid < 131) out[tid] = 0.f;          // out[128]=0, sim=0 (+atomics), far placeholder
    if (tid < 65) ints[tid] = 0;                 // cnt + bact[64]
}

// ---------------------------------------------------------------------------
// gemm1: topic_prob = f^T . tvn (fp32 VALU GEMM), ZERO LDS in the main loop.
// Each thread owns one s-column (s = s0 + lane): its f load is perfectly
// coalesced VMEM (L1-reused 4x across waves). Each wave owns a 32-k slice of
// tvn, loaded via wave-uniform SCALAR loads (s_load_dwordx8, SMEM pipe) ->
// FMAs are v_fmac(sgpr, vgpr). No barriers in the main loop; the DS pipe
// (the measured 2.25x bottleneck: VALUBusy 44.7% == 1/2.25) is bypassed.
// Grid 512 = 64 b x 8 s-tiles(64). Block 256 threads (4 waves, 8 waves/CU).
// Per-thread: 1s x 32k = 32 acc; row-norm nsq accumulates wave-locally.
__global__ __launch_bounds__(256) void gemm1_kernel(
    const float* __restrict__ f, const float* __restrict__ tvn,
    float* __restrict__ out_nn, float* __restrict__ tpnT,
    int* __restrict__ cnt, int* __restrict__ bact, int* __restrict__ alist)
{
    __shared__ float redp[4][64];         // per-wave row-sum partials
    __shared__ float rinvS[64];

    const int tid  = threadIdx.x;
    const int lane = tid & 63;
    const int wv   = __builtin_amdgcn_readfirstlane(tid >> 6);  // wave id 0..3, force SGPR
    const int b    = blockIdx.x >> 3;
    const int s0   = (blockIdx.x & 7) << 6;

    const float* fb = f + (size_t)b * D_ * S_ + s0 + lane;  // per-lane column
    const float* tw = tvn + wv * 32;                        // wave-uniform k-slice

    float acc[32];
#pragma unroll
    for (int j = 0; j < 32; ++j) acc[j] = 0.f;
    float nsq = 0.f;

#pragma unroll 4
    for (int d = 0; d < D_; ++d) {
        const float a = fb[(size_t)d * S_];       // coalesced vector load
        float w[32];
#pragma unroll
        for (int j = 0; j < 32; ++j) w[j] = tw[d*KP_ + j];  // uniform -> s_load
        nsq = fmaf(a, a, nsq);
#pragma unroll
        for (int j = 0; j < 32; ++j)
            acc[j] = fmaf(w[j], a, acc[j]);       // sgpr as src0
    }

    // ---- epilogue ----
    const float ninv = 1.0f / fmaxf(sqrtf(nsq), 1e-12f);
    const int bs0 = b * S_ + s0;

    float tq[32];
    float rowp = 0.f;
#pragma unroll
    for (int j = 0; j < 32; ++j) {
        tq[j] = acc[j] * ninv;
        acc[j] = (tq[j] > 0.3f) ? acc[j] : 0.f;   // topic_prob * mask in place
        rowp += acc[j];
    }
    // topic_prob_n transposed: lanes write consecutive bs -> coalesced b32
#pragma unroll
    for (int j = 0; j < 32; ++j) {
        const int k = wv*32 + j;
        if (k < K_) tpnT[(size_t)k * BS_ + bs0 + lane] = tq[j];
    }

    // row-sum across the 4 k-slices
    redp[wv][lane] = rowp;
    __syncthreads();
    if (tid < 64) {
        const float t = redp[0][tid] + redp[1][tid] + redp[2][tid] + redp[3][tid];
        rinvS[tid] = 1.0f / (t + 0.001f);
        if (t > 0.f) {                    // any unmasked concept in this row
            const int pos = atomicAdd(cnt, 1);
            alist[pos] = bs0 + tid;
            atomicAdd(&bact[b], 1);
        }
    }
    __syncthreads();
    const float rinv = rinvS[lane];
    float* ob = out_nn + (size_t)(bs0 + lane) * K_ + wv*32;
#pragma unroll
    for (int j = 0; j < 32; ++j) {
        if (wv*32 + j < K_) ob[j] = acc[j] * rinv;
    }
}

// ---------------------------------------------------------------------------
// gemm2p: blocks 0..127 sparse rec1 accumulation over active rows;
//         block 128 computes concept_far -> out[130].
__global__ __launch_bounds__(256) void gemm2p_kernel(
    const float* __restrict__ nn, const float* __restrict__ W1,
    float* __restrict__ hsum, const int* __restrict__ cnt,
    const int* __restrict__ alist, const float* __restrict__ tvn,
    float* __restrict__ out)
{
    __shared__ float red[256];
    const int tid = threadIdx.x;
    if (blockIdx.x == 128) {              // concept_far = (||sum_k tvn_col||^2 - K)/K^2
        float part = 0.f;
        for (int d = tid; d < D_; d += 256) {
            const float4* row = (const float4*)(tvn + (size_t)d * KP_);
            float s = 0.f;
#pragma unroll 8
            for (int i = 0; i < 32; ++i) { float4 v = row[i]; s += v.x + v.y + v.z + v.w; }
            part = fmaf(s, s, part);
        }
        red[tid] = part;
        __syncthreads();
        for (int s = 128; s > 0; s >>= 1) {
            if (tid < s) red[tid] += red[tid + s];
            __syncthreads();
        }
        if (tid == 0) out[130] = (red[0] - (float)K_) / ((float)K_ * (float)K_);
        return;
    }
    __shared__ float nl[K_];
    const int n = *cnt;
    for (int idx = blockIdx.x; idx < n; idx += 128) {
        const int bs = alist[idx];
        const int b  = bs >> 9;
        __syncthreads();
        if (tid < K_) nl[tid] = nn[(size_t)bs * K_ + tid];
        __syncthreads();
        for (int h = tid; h < H_; h += 256) {
            float a = 0.f;
#pragma unroll 4
            for (int k = 0; k < K_; ++k) a = fmaf(nl[k], W1[k*H_ + h], a);
            atomicAdd(&hsum[(size_t)b*H_ + h], fmaxf(a, 0.f));
        }
    }
}

// ---------------------------------------------------------------------------
// gemm3p: feat = (hsum . W2)/S fused into pred partial atomics.
// Inactive batch (the common case) -> immediate exit, pred stays b_cls.
__global__ __launch_bounds__(256) void gemm3p_kernel(
    const float* __restrict__ hsum, const float* __restrict__ W2,
    const float* __restrict__ Wc, const int* __restrict__ bact,
    float* __restrict__ out)
{
    const int b = blockIdx.x >> 2;
    if (bact[b] == 0) return;
    __shared__ float hl[H_];
    __shared__ float red[256];
    const int tid = threadIdx.x;
    const int d = ((blockIdx.x & 3) << 8) + tid;
    for (int h = tid; h < H_; h += 256) hl[h] = hsum[(size_t)b*H_ + h];
    __syncthreads();
    float a = 0.f;
    for (int h = 0; h < H_; ++h) a = fmaf(hl[h], W2[(size_t)h*D_ + d], a);
    a *= (1.0f/512.0f);                   // feat[b][d]
    const float p0 = a * Wc[d*2];
    const float p1 = a * Wc[d*2 + 1];
    red[tid] = p0;
    __syncthreads();
    for (int s = 128; s > 0; s >>= 1) {
        if (tid < s) red[tid] += red[tid + s];
        __syncthreads();
    }
    if (tid == 0) atomicAdd(&out[b*2], red[0]);
    __syncthreads();
    red[tid] = p1;
    __syncthreads();
    for (int s = 128; s > 0; s >>= 1) {
        if (tid < s) red[tid] += red[tid + s];
        __syncthreads();
    }
    if (tid == 0) atomicAdd(&out[b*2 + 1], red[0]);
}

// ---------------------------------------------------------------------------
// topk: per-concept top-16 sum over 32768; per-thread register top16 +
// register/shuffle tournament merge (no LDS candidate array).
// Adds -sum/1600 into out[129].
__global__ __launch_bounds__(256) void topk_kernel(const float* __restrict__ tpnT,
                                                   float* __restrict__ out)
{
    __shared__ float wvv[4];
    __shared__ int   wvi[4];
    const int tid = threadIdx.x;
    const int k = blockIdx.x;
    const float* col = tpnT + (size_t)k * BS_;
    float lst[16];
#pragma unroll
    for (int q = 0; q < 16; ++q) lst[q] = -3.4e38f;
    for (int i = tid; i < BS_; i += 256) {
        const float v = col[i];
        if (v > lst[0]) {                 // insert keeping ascending order
            float nl[16];
#pragma unroll
            for (int q = 0; q < 16; ++q) {
                const bool sh = (q < 15) ? (lst[q+1] < v) : false;
                nl[q] = sh ? lst[q+1] : ((lst[q] < v) ? v : lst[q]);
            }
#pragma unroll
            for (int q = 0; q < 16; ++q) lst[q] = nl[q];
        }
    }
    float sum = 0.f;
    for (int r = 0; r < 16; ++r) {
        float m = lst[0]; int mi = 0;
#pragma unroll
        for (int q = 1; q < 16; ++q) if (lst[q] > m) { m = lst[q]; mi = q; }
        int idx = (tid << 4) | mi;
        for (int off = 32; off > 0; off >>= 1) {
            const float om = __shfl_xor(m, off);
            const int   oi = __shfl_xor(idx, off);
            if (om > m) { m = om; idx = oi; }
        }
        if ((tid & 63) == 0) { wvv[tid >> 6] = m; wvi[tid >> 6] = idx; }
        __syncthreads();
        float gm = wvv[0]; int gi = wvi[0];
#pragma unroll
        for (int w = 1; w < 4; ++w) if (wvv[w] > gm) { gm = wvv[w]; gi = wvi[w]; }
        sum += gm;
        if (tid == (gi >> 4)) {
            const int cq = gi & 15;
#pragma unroll
            for (int q = 0; q < 16; ++q) if (q == cq) lst[q] = -3.4e38f;
        }
        __syncthreads();
    }
    if (tid == 0) atomicAdd(&out[129], sum * (-1.0f/1600.0f));
}

// ---------------------------------------------------------------------------
extern "C" void kernel_launch(void* const* d_in, const int* in_sizes, int n_in,
                              void* d_out, int out_size, void* d_ws, size_t ws_size,
                              hipStream_t stream)
{
    (void)in_sizes; (void)n_in; (void)out_size; (void)ws_size;
    const float* f   = (const float*)d_in[0];
    const float* tv  = (const float*)d_in[1];
    const float* W1  = (const float*)d_in[2];
    const float* W2  = (const float*)d_in[3];
    const float* Wc  = (const float*)d_in[4];
    const float* bc  = (const float*)d_in[5];
    float* out = (float*)d_out;
    float* ws  = (float*)d_ws;

    float* tvn  = ws + OFF_TVN;
    float* tpnT = ws + OFF_TPNT;
    float* hsum = ws + OFF_HSUM;
    int*   ints = (int*)(ws + OFF_INTS);
    int* cnt   = ints;
    int* bact  = ints + 1;
    int* alist = ints + 65;
    float* out_nn = out + 131;

    hipLaunchKernelGGL(prep_kernel,   dim3(641), dim3(256), 0, stream, tv, bc, tvn, hsum, ints, out);
    hipLaunchKernelGGL(gemm1_kernel,  dim3(512), dim3(256), 0, stream, f, tvn, out_nn, tpnT, cnt, bact, alist);
    hipLaunchKernelGGL(gemm2p_kernel, dim3(129), dim3(256), 0, stream, out_nn, W1, hsum, cnt, alist, tvn, out);
    hipLaunchKernelGGL(gemm3p_kernel, dim3(256), dim3(256), 0, stream, hsum, W2, Wc, bact, out);
    hipLaunchKernelGGL(topk_kernel,   dim3(K_),  dim3(256), 0, stream, tpnT, out);
}

// Round 9
// 393.954 us; speedup vs baseline: 1.1338x; 1.1338x over previous
//
#include <hip/hip_runtime.h>
#include <cstdint>
#include <cstddef>

#define B_  64
#define D_  1024
#define S_  512
#define K_  100
#define KP_ 128
#define H_  2048
#define BS_ (B_*S_)   // 32768

typedef __attribute__((ext_vector_type(8))) short bf16x8;
typedef __attribute__((ext_vector_type(4))) float f32x4;
typedef unsigned short ushort_t;
typedef unsigned int   uint_t;

// ---- workspace layout (float offsets) ----
static constexpr size_t OFF_TVN   = 0;                           // [1024][128] f32 (concept_far)
static constexpr size_t OFF_TVNTH = 131072;                      // [128][1024] bf16-hi (ushort)
static constexpr size_t OFF_TVNTL = 196608;                      // [128][1024] bf16-lo
static constexpr size_t OFF_TPNT  = 262144;                      // [100][32768] f32
static constexpr size_t OFF_HSUM  = OFF_TPNT + (size_t)K_*BS_;   // [64][2048]
static constexpr size_t OFF_INTS  = OFF_HSUM + (size_t)B_*H_;    // cnt, bact[64], alist[32768]

__device__ __forceinline__ ushort_t bfrte(float x) {             // fp32 -> bf16 RTNE
    uint_t u = __float_as_uint(x);
    u += 0x7FFFu + ((u >> 16) & 1u);
    return (ushort_t)(u >> 16);
}
__device__ __forceinline__ float bfback(ushort_t h) {
    return __uint_as_float(((uint_t)h) << 16);
}

// ---------------------------------------------------------------------------
// prep: blocks 0..127 normalize topic cols -> tvn[1024][128] AND bf16-split
//       transposed tvnT_hi/lo[128][1024]; blocks 128..639 zero hsum;
//       block 640: out scalar init + ints zero.
__global__ __launch_bounds__(256) void prep_kernel(
    const float* __restrict__ tv, const float* __restrict__ bc,
    float* __restrict__ tvn, ushort_t* __restrict__ tvnth, ushort_t* __restrict__ tvntl,
    float* __restrict__ hsum, int* __restrict__ ints, float* __restrict__ out)
{
    __shared__ float red[256];
    const int tid = threadIdx.x;
    const int blk = blockIdx.x;
    if (blk < KP_) {
        const int k = blk;
        if (k >= K_) {
            for (int d = tid; d < D_; d += 256) {
                tvn[d*KP_ + k] = 0.f;
                tvnth[(size_t)k*D_ + d] = 0;
                tvntl[(size_t)k*D_ + d] = 0;
            }
            return;
        }
        float ss = 0.f;
        for (int d = tid; d < D_; d += 256) { float v = tv[d*K_ + k]; ss = fmaf(v, v, ss); }
        red[tid] = ss;
        __syncthreads();
        for (int s = 128; s > 0; s >>= 1) {
            if (tid < s) red[tid] += red[tid + s];
            __syncthreads();
        }
        const float inv = 1.0f / fmaxf(sqrtf(red[0]), 1e-12f);
        for (int d = tid; d < D_; d += 256) {
            const float v = tv[d*K_ + k] * inv;
            tvn[d*KP_ + k] = v;
            const ushort_t hb = bfrte(v);
            const ushort_t lb = bfrte(v - bfback(hb));
            tvnth[(size_t)k*D_ + d] = hb;
            tvntl[(size_t)k*D_ + d] = lb;
        }
        return;
    }
    if (blk < KP_ + 512) {
        hsum[(blk - KP_)*256 + tid] = 0.f;
        return;
    }
    if (tid < 128)      out[tid] = bc[tid & 1];
    else if (tid < 131) out[tid] = 0.f;
    if (tid < 65) ints[tid] = 0;
}

// ---------------------------------------------------------------------------
// gemm1 (MFMA bf16-split): topic_prob = tvn^T(A, M=topics) . f(B, N=s).
// 16x16x32 bf16 MFMA, 3-term split (AhBh + AhBl + AlBh), fp32 accumulate.
// Each WAVE owns a 16-s tile x all 128 topics (8 M-tiles, acc 32 f32/lane).
// B (f) staged per-wave in private LDS (pack-2 bf16, stride 20 dwords,
// 2-way-conflict-free writes, b128 frag reads). A-frags straight from
// global (tvnT hi/lo, L1/L2 resident). NO __syncthreads in the main loop;
// f loads prefetched 2 K-steps ahead. Grid 512 x 256 thr (2048 waves).
__global__ __launch_bounds__(256) void gemm1_kernel(
    const float* __restrict__ f,
    const ushort_t* __restrict__ tvnth, const ushort_t* __restrict__ tvntl,
    float* __restrict__ out_nn, float* __restrict__ tpnT,
    int* __restrict__ cnt, int* __restrict__ bact, int* __restrict__ alist)
{
    __shared__ __align__(16) uint_t bstg[4][2][2][320];  // [wave][dbuf][hi/lo][s*20 + dpair]

    const int tid  = threadIdx.x;
    const int lane = tid & 63;
    const int wv   = tid >> 6;
    const int g    = lane >> 4;          // 0..3
    const int h    = lane & 15;          // 0..15
    const int b    = blockIdx.x >> 3;
    const int scol = ((blockIdx.x & 7) << 6) + (wv << 4) + h;   // s within batch row

    const float* fb = f + (size_t)b * D_ * S_ + scol;

    f32x4 acc[8];
#pragma unroll
    for (int m = 0; m < 8; ++m) acc[m] = (f32x4){0.f, 0.f, 0.f, 0.f};
    float nsq = 0.f;

    float fvA[8], fvB[8];

    // ---- prologue: load f for steps 0,1; stage step 0 into buf0 ----
#pragma unroll
    for (int i = 0; i < 4; ++i) {
        const int d = (g + (i << 2)) << 1;              // step 0: d0 = 0
        fvA[2*i]   = fb[(size_t)d * S_];
        fvA[2*i+1] = fb[(size_t)(d + 1) * S_];
    }
#pragma unroll
    for (int i = 0; i < 4; ++i) {
        const int d = 32 + ((g + (i << 2)) << 1);       // step 1
        fvB[2*i]   = fb[(size_t)d * S_];
        fvB[2*i+1] = fb[(size_t)(d + 1) * S_];
    }
#pragma unroll
    for (int i = 0; i < 4; ++i) {                       // cvt step0 -> buf0
        const float v0 = fvA[2*i], v1 = fvA[2*i+1];
        nsq = fmaf(v0, v0, fmaf(v1, v1, nsq));
        const ushort_t h0 = bfrte(v0), h1 = bfrte(v1);
        const ushort_t l0 = bfrte(v0 - bfback(h0)), l1 = bfrte(v1 - bfback(h1));
        bstg[wv][0][0][h*20 + g + (i << 2)] = (uint_t)h0 | ((uint_t)h1 << 16);
        bstg[wv][0][1][h*20 + g + (i << 2)] = (uint_t)l0 | ((uint_t)l1 << 16);
    }

#define STEPBODY(STEP, FVC, FVL, DOLOAD)                                          \
    {                                                                             \
        const int cur = (STEP) & 1;                                               \
        const bf16x8 bh = *(const bf16x8*)&bstg[wv][cur][0][h*20 + (g << 2)];     \
        const bf16x8 bl = *(const bf16x8*)&bstg[wv][cur][1][h*20 + (g << 2)];     \
        if (DOLOAD) {                                                             \
            _Pragma("unroll")                                                     \
            for (int i2 = 0; i2 < 4; ++i2) {                                      \
                const int d = ((STEP) + 2)*32 + ((g + (i2 << 2)) << 1);           \
                FVL[2*i2]   = fb[(size_t)d * S_];                                 \
                FVL[2*i2+1] = fb[(size_t)(d + 1) * S_];                           \
            }                                                                     \
        }                                                                         \
        bf16x8 ah[8], al[8];                                                      \
        _Pragma("unroll")                                                         \
        for (int m = 0; m < 8; ++m) {                                             \
            const size_t ai = (size_t)((m << 4) + h)*D_ + (STEP)*32 + (g << 3);   \
            ah[m] = *(const bf16x8*)(tvnth + ai);                                 \
            al[m] = *(const bf16x8*)(tvntl + ai);                                 \
        }                                                                         \
        if ((STEP) < 31) {                                                        \
            _Pragma("unroll")                                                     \
            for (int i2 = 0; i2 < 4; ++i2) {                                      \
                const float v0 = FVC[2*i2], v1 = FVC[2*i2+1];                     \
                nsq = fmaf(v0, v0, fmaf(v1, v1, nsq));                            \
                const ushort_t h0 = bfrte(v0), h1 = bfrte(v1);                    \
                const ushort_t l0 = bfrte(v0 - bfback(h0));                       \
                const ushort_t l1 = bfrte(v1 - bfback(h1));                       \
                bstg[wv][cur ^ 1][0][h*20 + g + (i2 << 2)] =                      \
                    (uint_t)h0 | ((uint_t)h1 << 16);                              \
                bstg[wv][cur ^ 1][1][h*20 + g + (i2 << 2)] =                      \
                    (uint_t)l0 | ((uint_t)l1 << 16);                              \
            }                                                                     \
        }                                                                         \
        _Pragma("unroll")                                                         \
        for (int m = 0; m < 8; ++m) {                                             \
            acc[m] = __builtin_amdgcn_mfma_f32_16x16x32_bf16(ah[m], bh, acc[m], 0, 0, 0); \
            acc[m] = __builtin_amdgcn_mfma_f32_16x16x32_bf16(ah[m], bl, acc[m], 0, 0, 0); \
            acc[m] = __builtin_amdgcn_mfma_f32_16x16x32_bf16(al[m], bh, acc[m], 0, 0, 0); \
        }                                                                         \
    }

    for (int step = 0; step < 32; step += 2) {
        STEPBODY(step,     fvB, fvA, (step < 30));      // consume fvB (step+1 data), load step+2
        STEPBODY(step + 1, fvA, fvB, (step + 1 < 30));
    }
#undef STEPBODY

    // ---- epilogue (wave-local; no barriers) ----
    nsq += __shfl_xor(nsq, 16);
    nsq += __shfl_xor(nsq, 32);
    const float ninv = 1.0f / fmaxf(sqrtf(nsq), 1e-12f);
    const int bs = b * S_ + ((blockIdx.x & 7) << 6) + (wv << 4) + h;

    float rowp = 0.f;
#pragma unroll
    for (int m = 0; m < 8; ++m) {
#pragma unroll
        for (int r = 0; r < 4; ++r) {
            const int topic = (m << 4) + (g << 2) + r;
            const float tp = acc[m][r];
            const float tq = tp * ninv;
            const float tpm = (tq > 0.3f) ? tp : 0.f;    // topic_prob * mask
            if (topic < K_) tpnT[(size_t)topic * BS_ + bs] = tq;
            acc[m][r] = tpm;
            rowp += tpm;
        }
    }
    rowp += __shfl_xor(rowp, 16);
    rowp += __shfl_xor(rowp, 32);
    const float rinv = 1.0f / (rowp + 0.001f);
    if (g == 0 && rowp > 0.f) {                          // one lane per s-row
        const int pos = atomicAdd(cnt, 1);
        alist[pos] = bs;
        atomicAdd(&bact[b], 1);
    }
    float* ob = out_nn + (size_t)bs * K_;
#pragma unroll
    for (int m = 0; m < 8; ++m) {
#pragma unroll
        for (int r = 0; r < 4; ++r) {
            const int topic = (m << 4) + (g << 2) + r;
            if (topic < K_) ob[topic] = acc[m][r] * rinv;
        }
    }
}

// ---------------------------------------------------------------------------
// gemm2p: blocks 0..127 sparse rec1 accumulation over active rows;
//         block 128 computes concept_far -> out[130].
__global__ __launch_bounds__(256) void gemm2p_kernel(
    const float* __restrict__ nn, const float* __restrict__ W1,
    float* __restrict__ hsum, const int* __restrict__ cnt,
    const int* __restrict__ alist, const float* __restrict__ tvn,
    float* __restrict__ out)
{
    __shared__ float red[256];
    const int tid = threadIdx.x;
    if (blockIdx.x == 128) {
        float part = 0.f;
        for (int d = tid; d < D_; d += 256) {
            const float4* row = (const float4*)(tvn + (size_t)d * KP_);
            float s = 0.f;
#pragma unroll 8
            for (int i = 0; i < 32; ++i) { float4 v = row[i]; s += v.x + v.y + v.z + v.w; }
            part = fmaf(s, s, part);
        }
        red[tid] = part;
        __syncthreads();
        for (int s = 128; s > 0; s >>= 1) {
            if (tid < s) red[tid] += red[tid + s];
            __syncthreads();
        }
        if (tid == 0) out[130] = (red[0] - (float)K_) / ((float)K_ * (float)K_);
        return;
    }
    __shared__ float nl[K_];
    const int n = *cnt;
    for (int idx = blockIdx.x; idx < n; idx += 128) {
        const int bs = alist[idx];
        const int b  = bs >> 9;
        __syncthreads();
        if (tid < K_) nl[tid] = nn[(size_t)bs * K_ + tid];
        __syncthreads();
        for (int h = tid; h < H_; h += 256) {
            float a = 0.f;
#pragma unroll 4
            for (int k = 0; k < K_; ++k) a = fmaf(nl[k], W1[k*H_ + h], a);
            atomicAdd(&hsum[(size_t)b*H_ + h], fmaxf(a, 0.f));
        }
    }
}

// ---------------------------------------------------------------------------
// gemm3p: feat = (hsum . W2)/S fused into pred partial atomics.
__global__ __launch_bounds__(256) void gemm3p_kernel(
    const float* __restrict__ hsum, const float* __restrict__ W2,
    const float* __restrict__ Wc, const int* __restrict__ bact,
    float* __restrict__ out)
{
    const int b = blockIdx.x >> 2;
    if (bact[b] == 0) return;
    __shared__ float hl[H_];
    __shared__ float red[256];
    const int tid = threadIdx.x;
    const int d = ((blockIdx.x & 3) << 8) + tid;
    for (int h = tid; h < H_; h += 256) hl[h] = hsum[(size_t)b*H_ + h];
    __syncthreads();
    float a = 0.f;
    for (int h = 0; h < H_; ++h) a = fmaf(hl[h], W2[(size_t)h*D_ + d], a);
    a *= (1.0f/512.0f);
    const float p0 = a * Wc[d*2];
    const float p1 = a * Wc[d*2 + 1];
    red[tid] = p0;
    __syncthreads();
    for (int s = 128; s > 0; s >>= 1) {
        if (tid < s) red[tid] += red[tid + s];
        __syncthreads();
    }
    if (tid == 0) atomicAdd(&out[b*2], red[0]);
    __syncthreads();
    red[tid] = p1;
    __syncthreads();
    for (int s = 128; s > 0; s >>= 1) {
        if (tid < s) red[tid] += red[tid + s];
        __syncthreads();
    }
    if (tid == 0) atomicAdd(&out[b*2 + 1], red[0]);
}

// ---------------------------------------------------------------------------
// topk: per-concept top-16 sum; register top16 + shuffle tournament merge.
__global__ __launch_bounds__(256) void topk_kernel(const float* __restrict__ tpnT,
                                                   float* __restrict__ out)
{
    __shared__ float wvv[4];
    __shared__ int   wvi[4];
    const int tid = threadIdx.x;
    const int k = blockIdx.x;
    const float* col = tpnT + (size_t)k * BS_;
    float lst[16];
#pragma unroll
    for (int q = 0; q < 16; ++q) lst[q] = -3.4e38f;
    for (int i = tid; i < BS_; i += 256) {
        const float v = col[i];
        if (v > lst[0]) {
            float nl[16];
#pragma unroll
            for (int q = 0; q < 16; ++q) {
                const bool sh = (q < 15) ? (lst[q+1] < v) : false;
                nl[q] = sh ? lst[q+1] : ((lst[q] < v) ? v : lst[q]);
            }
#pragma unroll
            for (int q = 0; q < 16; ++q) lst[q] = nl[q];
        }
    }
    float sum = 0.f;
    for (int r = 0; r < 16; ++r) {
        float m = lst[0]; int mi = 0;
#pragma unroll
        for (int q = 1; q < 16; ++q) if (lst[q] > m) { m = lst[q]; mi = q; }
        int idx = (tid << 4) | mi;
        for (int off = 32; off > 0; off >>= 1) {
            const float om = __shfl_xor(m, off);
            const int   oi = __shfl_xor(idx, off);
            if (om > m) { m = om; idx = oi; }
        }
        if ((tid & 63) == 0) { wvv[tid >> 6] = m; wvi[tid >> 6] = idx; }
        __syncthreads();
        float gm = wvv[0]; int gi = wvi[0];
#pragma unroll
        for (int w = 1; w < 4; ++w) if (wvv[w] > gm) { gm = wvv[w]; gi = wvi[w]; }
        sum += gm;
        if (tid == (gi >> 4)) {
            const int cq = gi & 15;
#pragma unroll
            for (int q = 0; q < 16; ++q) if (q == cq) lst[q] = -3.4e38f;
        }
        __syncthreads();
    }
    if (tid == 0) atomicAdd(&out[129], sum * (-1.0f/1600.0f));
}

// ---------------------------------------------------------------------------
extern "C" void kernel_launch(void* const* d_in, const int* in_sizes, int n_in,
                              void* d_out, int out_size, void* d_ws, size_t ws_size,
                              hipStream_t stream)
{
    (void)in_sizes; (void)n_in; (void)out_size; (void)ws_size;
    const float* f   = (const float*)d_in[0];
    const float* tv  = (const float*)d_in[1];
    const float* W1  = (const float*)d_in[2];
    const float* W2  = (const float*)d_in[3];
    const float* Wc  = (const float*)d_in[4];
    const float* bc  = (const float*)d_in[5];
    float* out = (float*)d_out;
    float* ws  = (float*)d_ws;

    float*    tvn   = ws + OFF_TVN;
    ushort_t* tvnth = (ushort_t*)(ws + OFF_TVNTH);
    ushort_t* tvntl = (ushort_t*)(ws + OFF_TVNTL);
    float*    tpnT  = ws + OFF_TPNT;
    float*    hsum  = ws + OFF_HSUM;
    int*      ints  = (int*)(ws + OFF_INTS);
    int* cnt   = ints;
    int* bact  = ints + 1;
    int* alist = ints + 65;
    float* out_nn = out + 131;

    hipLaunchKernelGGL(prep_kernel,   dim3(641), dim3(256), 0, stream,
                       tv, bc, tvn, tvnth, tvntl, hsum, ints, out);
    hipLaunchKernelGGL(gemm1_kernel,  dim3(512), dim3(256), 0, stream,
                       f, tvnth, tvntl, out_nn, tpnT, cnt, bact, alist);
    hipLaunchKernelGGL(gemm2p_kernel, dim3(129), dim3(256), 0, stream,
                       out_nn, W1, hsum, cnt, alist, tvn, out);
    hipLaunchKernelGGL(gemm3p_kernel, dim3(256), dim3(256), 0, stream, hsum, W2, Wc, bact, out);
    hipLaunchKernelGGL(topk_kernel,   dim3(K_),  dim3(256), 0, stream, tpnT, out);
}